// Round 4
// baseline (130.453 us; speedup 1.0000x reference)
//
#include <hip/hip_runtime.h>

#define C 161
#define C3 4173281            // 161^3 cells
#define NVERT_ELEMS 12519843  // C3*3
#define APQ 4121600           // 161*160*160 quads per axis
#define TQ 12364800           // 3*APQ
#define TOTQ_ELEMS 49459200   // 4*TQ
#define NQB 48300             // TQ/256
#define NVB 16302             // ceil(C3/256)

// round f32 to nearest bf16 (RNE), return as f32
__device__ __forceinline__ float bf16r(float f) {
    union { float f; unsigned int u; } v; v.f = f;
    v.u += 0x7FFFu + ((v.u >> 16) & 1u);
    v.u &= 0xFFFF0000u;
    return v.f;
}

// general clamped sample of padded grid (pad 1.0); x,y,z padded coords
__device__ __forceinline__ float sampg(const float* __restrict__ g, int x, int y, int z) {
    int ux = x - 1, uy = y - 1, uz = z - 1;
    bool in = ((unsigned)ux < 160u) && ((unsigned)uy < 160u) && ((unsigned)uz < 160u);
    int cx = min(max(ux, 0), 159);
    int cy = min(max(uy, 0), 159);
    int cz = min(max(uz, 0), 159);
    float v = g[(cx * 160 + cy) * 160 + cz];
    return in ? v : 1.0f;
}

__device__ __forceinline__ void verts_body(int vb, int t,
                                           const float* __restrict__ grid,
                                           const float* __restrict__ deform,
                                           float* __restrict__ out,
                                           float* sh) {
    int tid = vb * 256 + t;
    int cz = tid % C;
    int t2 = tid / C;
    int cy = t2 % C;
    int cx = t2 / C;

    float gv[8], dx[8], dy[8], dz[8];
    bool fastxy = ((unsigned)(cx - 1) < 159u) & ((unsigned)(cy - 1) < 159u);
    if (fastxy) {
        // x,y interior; z boundary handled branchlessly
        int zl0 = max(cz - 1, 0);
        int zl1 = min(cz, 159);
        bool z0ok = cz >= 1, z1ok = cz <= 159;
        int base00 = ((cx - 1) * 160 + (cy - 1)) * 160;
#pragma unroll
        for (int bx = 0; bx < 2; ++bx)
#pragma unroll
            for (int by = 0; by < 2; ++by) {
                int c0 = bx * 4 + by * 2;
                int bi = base00 + bx * 25600 + by * 160;
                float g0 = grid[bi + zl0], g1 = grid[bi + zl1];
                gv[c0]     = z0ok ? g0 : 1.0f;
                gv[c0 + 1] = z1ok ? g1 : 1.0f;
                const float* d0 = deform + (size_t)(bi + zl0) * 3;
                const float* d1 = deform + (size_t)(bi + zl1) * 3;
                float a0 = d0[0], a1 = d0[1], a2 = d0[2];
                float b0 = d1[0], b1 = d1[1], b2 = d1[2];
                dx[c0] = z0ok ? a0 : 0.f; dy[c0] = z0ok ? a1 : 0.f; dz[c0] = z0ok ? a2 : 0.f;
                dx[c0 + 1] = z1ok ? b0 : 0.f; dy[c0 + 1] = z1ok ? b1 : 0.f; dz[c0 + 1] = z1ok ? b2 : 0.f;
            }
    } else {
#pragma unroll
        for (int c = 0; c < 8; ++c) {
            int bx = (c >> 2) & 1, by = (c >> 1) & 1, bz = c & 1;
            int x = cx + bx, y = cy + by, z = cz + bz;
            gv[c] = sampg(grid, x, y, z);
            int ux = x - 1, uy = y - 1, uz = z - 1;
            bool in = ((unsigned)ux < 160u) && ((unsigned)uy < 160u) && ((unsigned)uz < 160u);
            int ix = min(max(ux, 0), 159);
            int iy = min(max(uy, 0), 159);
            int iz = min(max(uz, 0), 159);
            const float* p = deform + ((size_t)((ix * 160 + iy) * 160 + iz)) * 3;
            float a0 = p[0], a1 = p[1], a2 = p[2];
            dx[c] = in ? a0 : 0.f;
            dy[c] = in ? a1 : 0.f;
            dz[c] = in ? a2 : 0.f;
        }
    }

    // per-corner interpolation weights over the 12 edges
    float w[8] = {0.f, 0.f, 0.f, 0.f, 0.f, 0.f, 0.f, 0.f};
    float cnt = 0.f;
#pragma unroll
    for (int a = 0; a < 3; ++a) {
        int step = (a == 0) ? 4 : ((a == 1) ? 2 : 1);
#pragma unroll
        for (int c = 0; c < 8; ++c) {
            if (c & step) continue;
            int c1 = c | step;
            float g0 = gv[c], g1 = gv[c1];
            bool cross = (g0 < 0.f) != (g1 < 0.f);
            float tt = g0 * __builtin_amdgcn_rcpf(g0 - g1);
            w[c]  += cross ? (1.f - tt) : 0.f;
            w[c1] += cross ? tt : 0.f;
            cnt   += cross ? 1.f : 0.f;
        }
    }

    float vs0 = 0.f, vs1 = 0.f, vs2 = 0.f;
#pragma unroll
    for (int c = 0; c < 8; ++c) {
        float fx = (float)(cx + ((c >> 2) & 1)) + dx[c];
        float fy = (float)(cy + ((c >> 1) & 1)) + dy[c];
        float fz = (float)(cz + (c & 1)) + dz[c];
        vs0 += w[c] * fx;
        vs1 += w[c] * fy;
        vs2 += w[c] * fz;
    }

    float v0, v1, v2;
    if (cnt > 0.f) {
        float inv = __builtin_amdgcn_rcpf(cnt);
        v0 = vs0 * inv; v1 = vs1 * inv; v2 = vs2 * inv;
    } else {
        v0 = v1 = v2 = 0.f;
    }
    const float s = 1.0f / 159.0f;
    int lt = t * 3;
    sh[lt + 0] = bf16r((v0 - 1.f) * s);
    sh[lt + 1] = bf16r((v1 - 1.f) * s);
    sh[lt + 2] = bf16r((v2 - 1.f) * s);

    __syncthreads();
    int base = vb * 768;
    int lim = NVERT_ELEMS - base;
    if (lim > 768) lim = 768;
    int off = t << 2;
    if (off + 4 <= lim) {
        float4 v = *(const float4*)&sh[off];
        *(float4*)(out + base + off) = v;
    } else if (off < lim) {
        for (int k = off; k < lim; ++k) out[base + k] = sh[k];
    }
}

// quad values (elements 0..3, bf16-rounded floats) for quad q
__device__ __forceinline__ float4 quad_vals(const float* __restrict__ grid, int q) {
    int a = q / APQ;
    int rem = q - a * APQ;
    int q0, q1, q2, q3;
    float g0, g1;
    if (a == 0) {
        int i2 = rem % 160; int r = rem / 160; int i1 = r % 160; int i0 = r / 160;
        int ex = i0, ey = i1 + 1, ez = i2 + 1;          // ex in [0,160]
        int pb = i1 * 160 + i2;                         // (ey-1)*160+(ez-1)
        int a0 = max(ex - 1, 0), a1 = min(ex, 159);
        float g0r = grid[a0 * 25600 + pb], g1r = grid[a1 * 25600 + pb];
        g0 = (ex >= 1)   ? g0r : 1.0f;
        g1 = (ex <= 159) ? g1r : 1.0f;
        int b = (ex * C + ey) * C + ez;
        q0 = b - C - 1; q1 = b - 1; q2 = b; q3 = b - C;
    } else if (a == 1) {
        int i2 = rem % 160; int r = rem / 160; int i1 = r % 161; int i0 = r / 161;
        int ex = i0 + 1, ey = i1, ez = i2 + 1;          // ey in [0,160]
        int pb = (ex - 1) * 25600 + i2;                 // + (ez-1)
        int a0 = max(ey - 1, 0), a1 = min(ey, 159);
        float g0r = grid[pb + a0 * 160], g1r = grid[pb + a1 * 160];
        g0 = (ey >= 1)   ? g0r : 1.0f;
        g1 = (ey <= 159) ? g1r : 1.0f;
        int b = (ex * C + ey) * C + ez;
        q0 = b - C * C - 1; q1 = b - 1; q2 = b; q3 = b - C * C;
    } else {
        int i2 = rem % 161; int r = rem / 161; int i1 = r % 160; int i0 = r / 160;
        int ex = i0 + 1, ey = i1 + 1, ez = i2;          // ez in [0,160]
        int pb = ((ex - 1) * 160 + i1) * 160;           // + (ey-1)
        int a0 = max(ez - 1, 0), a1 = min(ez, 159);
        float g0r = grid[pb + a0], g1r = grid[pb + a1];
        g0 = (ez >= 1)   ? g0r : 1.0f;
        g1 = (ez <= 159) ? g1r : 1.0f;
        int b = (ex * C + ey) * C + ez;
        q0 = b - C * C - C; q1 = b - C; q2 = b; q3 = b - C * C;
    }
    float4 w;
    bool m = (g0 < 0.f) != (g1 < 0.f);
    if (!m) {
        w.x = w.y = w.z = w.w = -1.0f;
    } else {
        int a0, a1, a2, a3;
        if (g0 < 0.f) { a0 = q0; a1 = q1; a2 = q2; a3 = q3; }
        else          { a0 = q3; a1 = q2; a2 = q1; a3 = q0; }
        w.x = bf16r((float)a0);
        w.y = bf16r((float)a1);
        w.z = bf16r((float)a2);
        w.w = bf16r((float)a3);
    }
    return w;
}

__device__ __forceinline__ void quads_body(int qb, int t,
                                           const float* __restrict__ grid,
                                           float* __restrict__ out,
                                           float* sh) {
    int q = (qb << 8) + t;
    float4 w = quad_vals(grid, q);
    // shifted window: sh[i] holds global element NVERT + 1 + 1024*qb + i
    sh[(t << 2) + 0] = w.y;
    sh[(t << 2) + 1] = w.z;
    sh[(t << 2) + 2] = w.w;
    if (t > 0) sh[(t << 2) - 1] = w.x;
    if (t == 255) {
        int q2 = q + 1;
        if (q2 < TQ) {
            float4 w2 = quad_vals(grid, q2);
            sh[1023] = w2.x;
        }
    }
    if (qb == 0 && t == 0) out[NVERT_ELEMS] = w.x;  // head element

    __syncthreads();
    int avail = TOTQ_ELEMS - 1 - (qb << 10);
    if (avail > 1024) avail = 1024;
    int off = t << 2;
    float* gp = out + NVERT_ELEMS + 1 + ((size_t)qb << 10);
    if (off + 4 <= avail) {
        float4 v = *(const float4*)&sh[off];
        *(float4*)(gp + off) = v;
    } else if (off < avail) {
        for (int k = off; k < avail; ++k) gp[k] = sh[k];
    }
}

// Interleaved fusion: groups of 4 blocks = 3 quads + 1 verts so both the
// write-BW-bound (quads) and VALU-bound (verts) populations stay co-resident.
__global__ __launch_bounds__(256) void dmc_fused(const float* __restrict__ grid,
                                                 const float* __restrict__ deform,
                                                 float* __restrict__ out) {
    __shared__ __align__(16) float sh[1024];
    int b = blockIdx.x;
    int g = b >> 2, r = b & 3;
    if (r == 3) {
        verts_body(g, threadIdx.x, grid, deform, out, sh);   // g in [0, NVB)
    } else {
        int qb = g * 3 + r;
        if (qb < NQB) quads_body(qb, threadIdx.x, grid, out, sh);
    }
}

extern "C" void kernel_launch(void* const* d_in, const int* in_sizes, int n_in,
                              void* d_out, int out_size, void* d_ws, size_t ws_size,
                              hipStream_t stream) {
    const float* grid   = (const float*)d_in[0];
    const float* deform = (const float*)d_in[1];
    float* out = (float*)d_out;
    hipLaunchKernelGGL(dmc_fused, dim3(4 * NVB), dim3(256), 0, stream, grid, deform, out);
}

// Round 5
// 86.935 us; speedup vs baseline: 1.5006x; 1.5006x over previous
//
#include <hip/hip_runtime.h>

#define C 161
#define C3 4173281            // 161^3 cells
#define NVERT_ELEMS 12519843  // C3*3
#define APQ 4121600           // 161*160*160 quads per axis
#define TQ 12364800           // 3*APQ
#define TOTQ_ELEMS 49459200   // 4*TQ
#define NQB 48300             // TQ/256
#define NVB 16302             // ceil(C3/256)

// round f32 to nearest bf16 (RNE), return as f32
__device__ __forceinline__ float bf16r(float f) {
    union { float f; unsigned int u; } v; v.f = f;
    v.u += 0x7FFFu + ((v.u >> 16) & 1u);
    v.u &= 0xFFFF0000u;
    return v.f;
}

// general clamped sample of padded grid (pad 1.0); x,y,z padded coords
__device__ __forceinline__ float sampg(const float* __restrict__ g, int x, int y, int z) {
    int ux = x - 1, uy = y - 1, uz = z - 1;
    bool in = ((unsigned)ux < 160u) && ((unsigned)uy < 160u) && ((unsigned)uz < 160u);
    int cx = min(max(ux, 0), 159);
    int cy = min(max(uy, 0), 159);
    int cz = min(max(uz, 0), 159);
    float v = g[(cx * 160 + cy) * 160 + cz];
    return in ? v : 1.0f;
}

__global__ __launch_bounds__(256) void verts_kernel(const float* __restrict__ grid,
                                                    const float* __restrict__ deform,
                                                    float* __restrict__ out) {
    __shared__ __align__(16) float sv[768];
    int tid = blockIdx.x * 256 + threadIdx.x;
    int cz = tid % C;
    int t2 = tid / C;
    int cy = t2 % C;
    int cx = t2 / C;

    float gv[8], px[8], py[8], pz[8];
    // wave-uniform fast path: every lane's 8 corners strictly in-bounds
    bool interior = ((unsigned)(cx - 1) < 159u) & ((unsigned)(cy - 1) < 159u) &
                    ((unsigned)(cz - 1) < 159u);
    if (__all(interior)) {
        int base = ((cx - 1) * 160 + (cy - 1)) * 160 + (cz - 1);
#pragma unroll
        for (int c = 0; c < 8; ++c) {
            int bx = (c >> 2) & 1, by = (c >> 1) & 1, bz = c & 1;
            int idx = base + bx * 25600 + by * 160 + bz;
            gv[c] = grid[idx];
            const float* p = deform + (size_t)idx * 3;
            px[c] = (float)(cx + bx) + p[0];
            py[c] = (float)(cy + by) + p[1];
            pz[c] = (float)(cz + bz) + p[2];
        }
    } else {
#pragma unroll
        for (int c = 0; c < 8; ++c) {
            int bx = (c >> 2) & 1, by = (c >> 1) & 1, bz = c & 1;
            int x = cx + bx, y = cy + by, z = cz + bz;
            gv[c] = sampg(grid, x, y, z);
            int ux = x - 1, uy = y - 1, uz = z - 1;
            bool in = ((unsigned)ux < 160u) && ((unsigned)uy < 160u) && ((unsigned)uz < 160u);
            int ix = min(max(ux, 0), 159);
            int iy = min(max(uy, 0), 159);
            int iz = min(max(uz, 0), 159);
            const float* p = deform + ((size_t)((ix * 160 + iy) * 160 + iz)) * 3;
            float a0 = p[0], a1 = p[1], a2 = p[2];
            px[c] = (float)x + (in ? a0 : 0.f);
            py[c] = (float)y + (in ? a1 : 0.f);
            pz[c] = (float)z + (in ? a2 : 0.f);
        }
    }

    float vs0 = 0.f, vs1 = 0.f, vs2 = 0.f, cnt = 0.f;
#pragma unroll
    for (int a = 0; a < 3; ++a) {
        int step = (a == 0) ? 4 : ((a == 1) ? 2 : 1);
#pragma unroll
        for (int c = 0; c < 8; ++c) {
            if (c & step) continue;
            int c1 = c | step;
            float g0 = gv[c], g1 = gv[c1];
            if ((g0 < 0.f) != (g1 < 0.f)) {
                float tt = g0 * __builtin_amdgcn_rcpf(g0 - g1);
                vs0 += px[c] + tt * (px[c1] - px[c]);
                vs1 += py[c] + tt * (py[c1] - py[c]);
                vs2 += pz[c] + tt * (pz[c1] - pz[c]);
                cnt += 1.f;
            }
        }
    }

    float v0, v1, v2;
    if (cnt > 0.f) {
        float inv = __builtin_amdgcn_rcpf(cnt);
        v0 = vs0 * inv; v1 = vs1 * inv; v2 = vs2 * inv;
    } else {
        v0 = v1 = v2 = 0.f;
    }
    const float s = 1.0f / 159.0f;
    int lt = threadIdx.x * 3;
    sv[lt + 0] = bf16r((v0 - 1.f) * s);
    sv[lt + 1] = bf16r((v1 - 1.f) * s);
    sv[lt + 2] = bf16r((v2 - 1.f) * s);

    __syncthreads();
    int base = blockIdx.x * 768;
    int lim = NVERT_ELEMS - base;
    if (lim > 768) lim = 768;
    int off = threadIdx.x << 2;
    if (off + 4 <= lim) {
        float4 v = *(const float4*)&sv[off];
        *(float4*)(out + base + off) = v;
    } else if (off < lim) {
        for (int k = off; k < lim; ++k) out[base + k] = sv[k];
    }
}

// quad values (elements 0..3, bf16-rounded floats) for quad q; axis-specialized loads
__device__ __forceinline__ float4 quad_vals(const float* __restrict__ grid, int q) {
    int a = q / APQ;
    int rem = q - a * APQ;
    int q0, q1, q2, q3;
    float g0, g1;
    if (a == 0) {
        int i2 = rem % 160; int r = rem / 160; int i1 = r % 160; int i0 = r / 160;
        int ex = i0, ey = i1 + 1, ez = i2 + 1;          // ex in [0,160]
        int pb = i1 * 160 + i2;
        int a0 = max(ex - 1, 0), a1 = min(ex, 159);
        float g0r = grid[a0 * 25600 + pb], g1r = grid[a1 * 25600 + pb];
        g0 = (ex >= 1)   ? g0r : 1.0f;
        g1 = (ex <= 159) ? g1r : 1.0f;
        int b = (ex * C + ey) * C + ez;
        q0 = b - C - 1; q1 = b - 1; q2 = b; q3 = b - C;
    } else if (a == 1) {
        int i2 = rem % 160; int r = rem / 160; int i1 = r % 161; int i0 = r / 161;
        int ex = i0 + 1, ey = i1, ez = i2 + 1;          // ey in [0,160]
        int pb = (ex - 1) * 25600 + i2;
        int a0 = max(ey - 1, 0), a1 = min(ey, 159);
        float g0r = grid[pb + a0 * 160], g1r = grid[pb + a1 * 160];
        g0 = (ey >= 1)   ? g0r : 1.0f;
        g1 = (ey <= 159) ? g1r : 1.0f;
        int b = (ex * C + ey) * C + ez;
        q0 = b - C * C - 1; q1 = b - 1; q2 = b; q3 = b - C * C;
    } else {
        int i2 = rem % 161; int r = rem / 161; int i1 = r % 160; int i0 = r / 160;
        int ex = i0 + 1, ey = i1 + 1, ez = i2;          // ez in [0,160]
        int pb = ((ex - 1) * 160 + i1) * 160;
        int a0 = max(ez - 1, 0), a1 = min(ez, 159);
        float g0r = grid[pb + a0], g1r = grid[pb + a1];
        g0 = (ez >= 1)   ? g0r : 1.0f;
        g1 = (ez <= 159) ? g1r : 1.0f;
        int b = (ex * C + ey) * C + ez;
        q0 = b - C * C - C; q1 = b - C; q2 = b; q3 = b - C * C;
    }
    float4 w;
    bool m = (g0 < 0.f) != (g1 < 0.f);
    if (!m) {
        w.x = w.y = w.z = w.w = -1.0f;
    } else {
        int a0, a1, a2, a3;
        if (g0 < 0.f) { a0 = q0; a1 = q1; a2 = q2; a3 = q3; }
        else          { a0 = q3; a1 = q2; a2 = q1; a3 = q0; }
        w.x = bf16r((float)a0);
        w.y = bf16r((float)a1);
        w.z = bf16r((float)a2);
        w.w = bf16r((float)a3);
    }
    return w;
}

__global__ __launch_bounds__(256) void quads_kernel(const float* __restrict__ grid,
                                                    float* __restrict__ out) {
    __shared__ __align__(16) float sq[1024];
    int b = blockIdx.x, t = threadIdx.x;
    int q = (b << 8) + t;
    float4 w = quad_vals(grid, q);
    // shifted window: sq[i] holds global element NVERT + 1 + 1024*b + i
    sq[(t << 2) + 0] = w.y;
    sq[(t << 2) + 1] = w.z;
    sq[(t << 2) + 2] = w.w;
    if (t > 0) sq[(t << 2) - 1] = w.x;
    if (t == 255) {
        int q2 = q + 1;
        if (q2 < TQ) {
            float4 w2 = quad_vals(grid, q2);
            sq[1023] = w2.x;
        }
    }
    if (b == 0 && t == 0) out[NVERT_ELEMS] = w.x;  // head element

    __syncthreads();
    int avail = TOTQ_ELEMS - 1 - (b << 10);
    if (avail > 1024) avail = 1024;
    int off = t << 2;
    float* gp = out + NVERT_ELEMS + 1 + ((size_t)b << 10);
    if (off + 4 <= avail) {
        float4 v = *(const float4*)&sq[off];
        *(float4*)(gp + off) = v;
    } else if (off < avail) {
        for (int k = off; k < avail; ++k) gp[k] = sq[k];
    }
}

extern "C" void kernel_launch(void* const* d_in, const int* in_sizes, int n_in,
                              void* d_out, int out_size, void* d_ws, size_t ws_size,
                              hipStream_t stream) {
    const float* grid   = (const float*)d_in[0];
    const float* deform = (const float*)d_in[1];
    float* out = (float*)d_out;

    hipLaunchKernelGGL(verts_kernel, dim3(NVB), dim3(256), 0, stream, grid, deform, out);
    hipLaunchKernelGGL(quads_kernel, dim3(NQB), dim3(256), 0, stream, grid, out);
}